// Round 5
// baseline (11815.154 us; speedup 1.0000x reference)
//
#include <hip/hip_runtime.h>

#define B_ 2
#define L_ 2048
#define DM 1024
#define H_ 16
#define DK 64
#define ROWS (B_*L_)   // 4096

typedef _Float16 f16x8 __attribute__((ext_vector_type(8)));
typedef float    f32x4 __attribute__((ext_vector_type(4)));
typedef unsigned short us8 __attribute__((ext_vector_type(8)));
typedef unsigned short us4v __attribute__((ext_vector_type(4)));

__device__ __forceinline__ unsigned short f2h(float f) {
    _Float16 h = (_Float16)f;
    return __builtin_bit_cast(unsigned short, h);
}
__device__ __forceinline__ float h2f(unsigned short u) {
    return (float)__builtin_bit_cast(_Float16, u);
}
__device__ __forceinline__ f16x8 ld8h(const unsigned short* p) {
    return *reinterpret_cast<const f16x8*>(p);
}

#define MFMA(a, b, c) __builtin_amdgcn_mfma_f32_16x16x32_f16((a), (b), (c), 0, 0, 0)

// ---------------------------------------------------------------------------
// kcvt: f32 -> fp16 bulk convert (8 elems/thread)
// ---------------------------------------------------------------------------
__global__ __launch_bounds__(256) void kcvt(
    const float* __restrict__ src, unsigned short* __restrict__ dst)
{
    size_t i = ((size_t)blockIdx.x * 256 + threadIdx.x) * 8;
    const float4* s4 = (const float4*)(src + i);
    float4 a = s4[0], b = s4[1];
    us8 u;
    u[0] = f2h(a.x); u[1] = f2h(a.y); u[2] = f2h(a.z); u[3] = f2h(a.w);
    u[4] = f2h(b.x); u[5] = f2h(b.y); u[6] = f2h(b.z); u[7] = f2h(b.w);
    *(us8*)(dst + i) = u;
}

// ---------------------------------------------------------------------------
// K0: transpose per-head weights (f32) [3][H][DM][DK] -> fp16 [3][H][DK][DM]
// ---------------------------------------------------------------------------
__global__ __launch_bounds__(256) void k0_transpose_w(
    const float* __restrict__ wq,
    const float* __restrict__ wk,
    const float* __restrict__ wv,
    unsigned short* __restrict__ wt)
{
    __shared__ unsigned short tile[64][65];
    int bx = blockIdx.x;
    int which = bx / (H_ * 16);
    int rem   = bx % (H_ * 16);
    int h  = rem >> 4;
    int db = (rem & 15) * 64;
    const float* src = (which == 0) ? wq : (which == 1) ? wk : wv;

    int t = threadIdx.x;
    int r = t >> 2;
    int c = (t & 3) * 16;
    const float4* sp = (const float4*)(src + ((size_t)(h * DM + db + r)) * DK + c);
    #pragma unroll
    for (int i4 = 0; i4 < 4; i4++) {
        float4 f = sp[i4];
        tile[r][c + i4 * 4 + 0] = f2h(f.x);
        tile[r][c + i4 * 4 + 1] = f2h(f.y);
        tile[r][c + i4 * 4 + 2] = f2h(f.z);
        tile[r][c + i4 * 4 + 3] = f2h(f.w);
    }
    __syncthreads();

    int n   = t >> 2;
    int d16 = (t & 3) * 16;
    __align__(16) unsigned short ov[16];
    #pragma unroll
    for (int i = 0; i < 16; i++) ov[i] = tile[d16 + i][n];
    size_t off = (((size_t)which * H_ + h) * DK + n) * DM + db + d16;
    *(us8*)(wt + off)     = *(us8*)&ov[0];
    *(us8*)(wt + off + 8) = *(us8*)&ov[8];
}

// ---------------------------------------------------------------------------
// K1: fused q/k/v per-head projection GEMM, fp16, 2-stage fragment pipeline.
// which==2 (V): output transposed via LDS -> vt [H][DK][ROWS].
// ---------------------------------------------------------------------------
__global__ __launch_bounds__(256) void k1_proj_qkv(
    const unsigned short* __restrict__ xh,   // fp16 [3][ROWS][DM]
    const unsigned short* __restrict__ wt,   // fp16 [3][H][DK][DM]
    unsigned short* __restrict__ qh,         // fp16 [H][ROWS][DK]
    unsigned short* __restrict__ kh,         // fp16 [H][ROWS][DK]
    unsigned short* __restrict__ vt)         // fp16 [H][DK][ROWS]
{
    __shared__ unsigned short vtile[64][137];

    int bx = blockIdx.x;
    int which = bx / (H_ * 32);
    int rem   = bx % (H_ * 32);
    int h     = rem & 15;
    int mbase = (rem >> 4) * 128;

    const unsigned short* X = xh + (size_t)which * ROWS * DM;
    const unsigned short* W = wt + ((size_t)which * H_ + h) * DK * DM;

    int wave = threadIdx.x >> 6, lane = threadIdx.x & 63;
    int quad = lane >> 4, l16 = lane & 15;
    int row0 = mbase + wave * 32;

    const unsigned short* pa0 = X + (size_t)(row0 + l16) * DM + quad * 8;
    const unsigned short* pa1 = X + (size_t)(row0 + 16 + l16) * DM + quad * 8;
    const unsigned short* pb  = W + (size_t)l16 * DM + quad * 8;

    f32x4 acc[2][4];
    #pragma unroll
    for (int i = 0; i < 2; i++)
        #pragma unroll
        for (int j = 0; j < 4; j++) acc[i][j] = (f32x4)0.0f;

    // 2-stage rotating fragment buffers
    f16x8 fa0[2], fa1[2], fb[2][4];
    #pragma unroll
    for (int p = 0; p < 2; p++) {
        int d = p * 32;
        fa0[p] = ld8h(pa0 + d);
        fa1[p] = ld8h(pa1 + d);
        #pragma unroll
        for (int nt = 0; nt < 4; nt++)
            fb[p][nt] = ld8h(pb + (size_t)nt * 16 * DM + d);
    }

    int p = 0;
    for (int d = 0; d < DM; d += 32) {
        #pragma unroll
        for (int nt = 0; nt < 4; nt++) {
            acc[0][nt] = MFMA(fa0[p], fb[p][nt], acc[0][nt]);
            acc[1][nt] = MFMA(fa1[p], fb[p][nt], acc[1][nt]);
        }
        int dn = (d + 64) & (DM - 1);   // wraps harmlessly on last 2 iters
        fa0[p] = ld8h(pa0 + dn);
        fa1[p] = ld8h(pa1 + dn);
        #pragma unroll
        for (int nt = 0; nt < 4; nt++)
            fb[p][nt] = ld8h(pb + (size_t)nt * 16 * DM + dn);
        p ^= 1;
    }

    if (which < 2) {
        unsigned short* OUT = ((which == 0) ? qh : kh) + (size_t)h * ROWS * DK;
        #pragma unroll
        for (int mt = 0; mt < 2; mt++)
            #pragma unroll
            for (int nt = 0; nt < 4; nt++)
                #pragma unroll
                for (int r = 0; r < 4; r++) {
                    int row = row0 + mt * 16 + quad * 4 + r;
                    OUT[(size_t)row * DK + nt * 16 + l16] = f2h(acc[mt][nt][r]);
                }
    } else {
        #pragma unroll
        for (int mt = 0; mt < 2; mt++)
            #pragma unroll
            for (int nt = 0; nt < 4; nt++)
                #pragma unroll
                for (int r = 0; r < 4; r++) {
                    int rrel = wave * 32 + mt * 16 + quad * 4 + r;
                    vtile[nt * 16 + l16][rrel] = f2h(acc[mt][nt][r]);
                }
        __syncthreads();
        int t  = threadIdx.x;
        int dk = t >> 2;
        int sg = (t & 3) * 32;
        __align__(16) unsigned short ov[32];
        #pragma unroll
        for (int i = 0; i < 32; i++) ov[i] = vtile[dk][sg + i];
        unsigned short* dp = vt + ((size_t)h * DK + dk) * ROWS + mbase + sg;
        #pragma unroll
        for (int i8 = 0; i8 < 4; i8++)
            *(us8*)(dp + i8 * 8) = *(us8*)&ov[i8 * 8];
    }
}

// ---------------------------------------------------------------------------
// K2: flash attention, S^T orientation (A=K, B=Q) -> cheap per-lane softmax,
// packed b64 P-write, WAR-safe single-buffer prefetch of K and V fragments.
// ---------------------------------------------------------------------------
__global__ __launch_bounds__(256) void k2_attn(
    const unsigned short* __restrict__ qh,   // fp16 [H][ROWS][DK]
    const unsigned short* __restrict__ kh,   // fp16 [H][ROWS][DK]
    const unsigned short* __restrict__ vt,   // fp16 [H][DK][ROWS]
    unsigned short* __restrict__ x2)         // fp16 [ROWS][DM]
{
    __shared__ __align__(16) unsigned short pld[4][16][80];  // per-wave P tile

    int bx = blockIdx.x;
    int h  = bx >> 6;
    int b  = (bx >> 5) & 1;
    int qt = bx & 31;
    int qbase = qt * 64;

    const unsigned short* qhp = qh + ((size_t)h * ROWS + b * L_) * DK;
    const unsigned short* khp = kh + ((size_t)h * ROWS + b * L_) * DK;
    const unsigned short* vtp = vt + (size_t)h * DK * ROWS + b * L_;

    int wave = threadIdx.x >> 6, lane = threadIdx.x & 63;
    int quad = lane >> 4, l16 = lane & 15;

    int qrow = qbase + wave * 16 + l16;
    f16x8 qb0 = ld8h(qhp + (size_t)qrow * DK + quad * 8);
    f16x8 qb1 = ld8h(qhp + (size_t)qrow * DK + 32 + quad * 8);

    // K fragments (A-operand): lane m=l16 -> key, k=quad*8+j -> d
    f16x8 ka0[4], ka1[4], vb[2][4];
    #pragma unroll
    for (int nt = 0; nt < 4; nt++) {
        const unsigned short* kp = khp + (size_t)(nt * 16 + l16) * DK;
        ka0[nt] = ld8h(kp + quad * 8);
        ka1[nt] = ld8h(kp + 32 + quad * 8);
    }
    #pragma unroll
    for (int kk = 0; kk < 2; kk++)
        #pragma unroll
        for (int nt = 0; nt < 4; nt++)
            vb[kk][nt] = ld8h(vtp + (size_t)(nt * 16 + l16) * ROWS + kk * 32 + quad * 8);

    // per-lane online-softmax stats for COLUMN qrow=l16 (replicated over quads)
    float m_i = -1e30f, l_i = 0.0f;
    f32x4 o[4];
    #pragma unroll
    for (int nt = 0; nt < 4; nt++) o[nt] = (f32x4)0.0f;

    for (int kt = 0; kt < 32; kt++) {
        int kb  = kt * 64;
        int kbn = (kb + 64) & (L_ - 1);   // wrap: last prefetch reads valid junk

        // S^T = K Q^T : s[nt][r] = S[qrow=l16][key = kb + nt*16 + quad*4 + r]
        f32x4 s[4];
        #pragma unroll
        for (int nt = 0; nt < 4; nt++) s[nt] = (f32x4)0.0f;
        #pragma unroll
        for (int nt = 0; nt < 4; nt++) {
            s[nt] = MFMA(ka0[nt], qb0, s[nt]);
            s[nt] = MFMA(ka1[nt], qb1, s[nt]);
        }

        // prefetch K for next tile (WAR-safe: ka just consumed)
        #pragma unroll
        for (int nt = 0; nt < 4; nt++) {
            const unsigned short* kp = khp + (size_t)(kbn + nt * 16 + l16) * DK;
            ka0[nt] = ld8h(kp + quad * 8);
            ka1[nt] = ld8h(kp + 32 + quad * 8);
        }

        // online softmax: local reduce over 16 regs + 2 shuffle steps
        float mx = s[0][0];
        #pragma unroll
        for (int nt = 0; nt < 4; nt++)
            #pragma unroll
            for (int r = 0; r < 4; r++) mx = fmaxf(mx, s[nt][r]);
        mx = fmaxf(mx, __shfl_xor(mx, 16));
        mx = fmaxf(mx, __shfl_xor(mx, 32));
        float mnew  = fmaxf(m_i, mx);
        float alpha = __expf(m_i - mnew);
        float rs = 0.0f;
        #pragma unroll
        for (int nt = 0; nt < 4; nt++)
            #pragma unroll
            for (int r = 0; r < 4; r++) {
                float pv = __expf(s[nt][r] - mnew);
                s[nt][r] = pv;
                rs += pv;
            }
        rs += __shfl_xor(rs, 16);
        rs += __shfl_xor(rs, 32);
        l_i = l_i * alpha + rs;
        m_i = mnew;

        // rescale O: row quad*4+r needs alpha of column quad*4+r (lives at lane quad*4+r)
        #pragma unroll
        for (int r = 0; r < 4; r++) {
            float av = __shfl(alpha, quad * 4 + r);
            #pragma unroll
            for (int nt = 0; nt < 4; nt++) o[nt][r] *= av;
        }

        // P -> per-wave LDS: lane owns 4 consecutive keys per nt -> one b64 store
        #pragma unroll
        for (int nt = 0; nt < 4; nt++) {
            us4v pk;
            pk[0] = f2h(s[nt][0]); pk[1] = f2h(s[nt][1]);
            pk[2] = f2h(s[nt][2]); pk[3] = f2h(s[nt][3]);
            *(us4v*)&pld[wave][l16][nt * 16 + quad * 4] = pk;
        }

        // O += P V
        #pragma unroll
        for (int kk = 0; kk < 2; kk++) {
            f16x8 pa = *(const f16x8*)&pld[wave][l16][kk * 32 + quad * 8];
            #pragma unroll
            for (int nt = 0; nt < 4; nt++)
                o[nt] = MFMA(pa, vb[kk][nt], o[nt]);
        }

        // prefetch V for next tile (WAR-safe: vb just consumed)
        #pragma unroll
        for (int kk = 0; kk < 2; kk++)
            #pragma unroll
            for (int nt = 0; nt < 4; nt++)
                vb[kk][nt] = ld8h(vtp + (size_t)(nt * 16 + l16) * ROWS + kbn + kk * 32 + quad * 8);
    }

    // epilogue: /l_i, * qh, head-concat store (fp16)
    float linv = 1.0f / l_i;
    #pragma unroll
    for (int r = 0; r < 4; r++) {
        float lv = __shfl(linv, quad * 4 + r);
        int row = qbase + wave * 16 + quad * 4 + r;
        #pragma unroll
        for (int nt = 0; nt < 4; nt++) {
            int col = nt * 16 + l16;
            float qv = h2f(qhp[(size_t)row * DK + col]);
            float val = o[nt][r] * lv * qv;
            x2[((size_t)b * L_ + row) * DM + h * DK + col] = f2h(val);
        }
    }
}

// ---------------------------------------------------------------------------
// K3: output projection  out = X2 @ w_proj^T + b_proj  (2-stage pipeline)
// ---------------------------------------------------------------------------
__global__ __launch_bounds__(256) void k3_out_proj(
    const unsigned short* __restrict__ x2,     // fp16 [ROWS][DM]
    const unsigned short* __restrict__ wph,    // fp16 [DM][DM] (row = out dim)
    const float* __restrict__ bias,
    float* __restrict__ out)
{
    int bx = blockIdx.x;
    int mt  = bx >> 4;
    int ntb = bx & 15;
    int mbase = mt * 128, nbase = ntb * 64;

    int wave = threadIdx.x >> 6, lane = threadIdx.x & 63;
    int quad = lane >> 4, l16 = lane & 15;
    int row0 = mbase + wave * 32;

    const unsigned short* pa0 = x2 + (size_t)(row0 + l16) * DM + quad * 8;
    const unsigned short* pa1 = x2 + (size_t)(row0 + 16 + l16) * DM + quad * 8;
    const unsigned short* pb  = wph + (size_t)(nbase + l16) * DM + quad * 8;

    f32x4 acc[2][4];
    #pragma unroll
    for (int i = 0; i < 2; i++)
        #pragma unroll
        for (int j = 0; j < 4; j++) acc[i][j] = (f32x4)0.0f;

    f16x8 fa0[2], fa1[2], fb[2][4];
    #pragma unroll
    for (int p = 0; p < 2; p++) {
        int c = p * 32;
        fa0[p] = ld8h(pa0 + c);
        fa1[p] = ld8h(pa1 + c);
        #pragma unroll
        for (int nt = 0; nt < 4; nt++)
            fb[p][nt] = ld8h(pb + (size_t)nt * 16 * DM + c);
    }

    int p = 0;
    for (int c = 0; c < DM; c += 32) {
        #pragma unroll
        for (int nt = 0; nt < 4; nt++) {
            acc[0][nt] = MFMA(fa0[p], fb[p][nt], acc[0][nt]);
            acc[1][nt] = MFMA(fa1[p], fb[p][nt], acc[1][nt]);
        }
        int cn = (c + 64) & (DM - 1);
        fa0[p] = ld8h(pa0 + cn);
        fa1[p] = ld8h(pa1 + cn);
        #pragma unroll
        for (int nt = 0; nt < 4; nt++)
            fb[p][nt] = ld8h(pb + (size_t)nt * 16 * DM + cn);
        p ^= 1;
    }

    #pragma unroll
    for (int mt2 = 0; mt2 < 2; mt2++)
        #pragma unroll
        for (int nt = 0; nt < 4; nt++)
            #pragma unroll
            for (int r = 0; r < 4; r++) {
                int row = row0 + mt2 * 16 + quad * 4 + r;
                int col = nbase + nt * 16 + l16;
                out[(size_t)row * DM + col] = acc[mt2][nt][r] + bias[col];
            }
}

// ---------------------------------------------------------------------------
extern "C" void kernel_launch(void* const* d_in, const int* in_sizes, int n_in,
                              void* d_out, int out_size, void* d_ws, size_t ws_size,
                              hipStream_t stream)
{
    const float* q     = (const float*)d_in[0];
    const float* k     = (const float*)d_in[1];
    const float* v     = (const float*)d_in[2];
    const float* wqs   = (const float*)d_in[3];
    const float* wks   = (const float*)d_in[4];
    const float* wvs   = (const float*)d_in[5];
    const float* wproj = (const float*)d_in[6];
    const float* bproj = (const float*)d_in[7];
    float* out = (float*)d_out;

    char* ws = (char*)d_ws;
    #define MB (size_t)(1024 * 1024)
    unsigned short* xh  = (unsigned short*)(ws);            // 24 MB (3 x 8 MB)
    unsigned short* wt  = (unsigned short*)(ws + 24 * MB);  // 6 MB
    unsigned short* wph = (unsigned short*)(ws + 30 * MB);  // 2 MB
    unsigned short* qh  = (unsigned short*)(ws + 32 * MB);  // 8 MB
    unsigned short* kh  = (unsigned short*)(ws + 40 * MB);  // 8 MB
    unsigned short* vt  = (unsigned short*)(ws + 48 * MB);  // 8 MB
    unsigned short* x2  = (unsigned short*)(ws + 56 * MB);  // 8 MB (total 64 MB)

    kcvt<<<dim3((ROWS * DM) / (256 * 8)), dim3(256), 0, stream>>>(q, xh);
    kcvt<<<dim3((ROWS * DM) / (256 * 8)), dim3(256), 0, stream>>>(k, xh + (size_t)ROWS * DM);
    kcvt<<<dim3((ROWS * DM) / (256 * 8)), dim3(256), 0, stream>>>(v, xh + (size_t)2 * ROWS * DM);
    kcvt<<<dim3((DM * DM) / (256 * 8)), dim3(256), 0, stream>>>(wproj, wph);
    k0_transpose_w<<<dim3(3 * H_ * 16), dim3(256), 0, stream>>>(wqs, wks, wvs, wt);

    k1_proj_qkv<<<dim3(3 * H_ * 32), dim3(256), 0, stream>>>(xh, wt, qh, kh, vt);
    k2_attn<<<dim3(H_ * B_ * 32), dim3(256), 0, stream>>>(qh, kh, vt, x2);
    k3_out_proj<<<dim3((ROWS / 128) * (DM / 64)), dim3(256), 0, stream>>>(x2, wph, bproj, out);
}

// Round 6
// 539.829 us; speedup vs baseline: 21.8868x; 21.8868x over previous
//
#include <hip/hip_runtime.h>

#define B_ 2
#define L_ 2048
#define DM 1024
#define H_ 16
#define DK 64
#define ROWS (B_*L_)   // 4096

typedef _Float16 f16x8 __attribute__((ext_vector_type(8)));
typedef float    f32x4 __attribute__((ext_vector_type(4)));
typedef unsigned short us8 __attribute__((ext_vector_type(8)));
typedef unsigned short us4v __attribute__((ext_vector_type(4)));

__device__ __forceinline__ unsigned short f2h(float f) {
    _Float16 h = (_Float16)f;
    return __builtin_bit_cast(unsigned short, h);
}
__device__ __forceinline__ float h2f(unsigned short u) {
    return (float)__builtin_bit_cast(_Float16, u);
}
__device__ __forceinline__ f16x8 ld8h(const unsigned short* p) {
    return *reinterpret_cast<const f16x8*>(p);
}

#define MFMA(a, b, c) __builtin_amdgcn_mfma_f32_16x16x32_f16((a), (b), (c), 0, 0, 0)

// ---------------------------------------------------------------------------
// kcvt: f32 -> fp16 bulk convert (8 elems/thread)
// ---------------------------------------------------------------------------
__global__ __launch_bounds__(256) void kcvt(
    const float* __restrict__ src, unsigned short* __restrict__ dst)
{
    size_t i = ((size_t)blockIdx.x * 256 + threadIdx.x) * 8;
    const float4* s4 = (const float4*)(src + i);
    float4 a = s4[0], b = s4[1];
    us8 u;
    u[0] = f2h(a.x); u[1] = f2h(a.y); u[2] = f2h(a.z); u[3] = f2h(a.w);
    u[4] = f2h(b.x); u[5] = f2h(b.y); u[6] = f2h(b.z); u[7] = f2h(b.w);
    *(us8*)(dst + i) = u;
}

// ---------------------------------------------------------------------------
// K0: transpose per-head weights (f32) [3][H][DM][DK] -> fp16 [3][H][DK][DM]
// ---------------------------------------------------------------------------
__global__ __launch_bounds__(256) void k0_transpose_w(
    const float* __restrict__ wq,
    const float* __restrict__ wk,
    const float* __restrict__ wv,
    unsigned short* __restrict__ wt)
{
    __shared__ unsigned short tile[64][65];
    int bx = blockIdx.x;
    int which = bx / (H_ * 16);
    int rem   = bx % (H_ * 16);
    int h  = rem >> 4;
    int db = (rem & 15) * 64;
    const float* src = (which == 0) ? wq : (which == 1) ? wk : wv;

    int t = threadIdx.x;
    int r = t >> 2;
    int c = (t & 3) * 16;
    const float4* sp = (const float4*)(src + ((size_t)(h * DM + db + r)) * DK + c);
    #pragma unroll
    for (int i4 = 0; i4 < 4; i4++) {
        float4 f = sp[i4];
        tile[r][c + i4 * 4 + 0] = f2h(f.x);
        tile[r][c + i4 * 4 + 1] = f2h(f.y);
        tile[r][c + i4 * 4 + 2] = f2h(f.z);
        tile[r][c + i4 * 4 + 3] = f2h(f.w);
    }
    __syncthreads();

    int n   = t >> 2;
    int d16 = (t & 3) * 16;
    __align__(16) unsigned short ov[16];
    #pragma unroll
    for (int i = 0; i < 16; i++) ov[i] = tile[d16 + i][n];
    size_t off = (((size_t)which * H_ + h) * DK + n) * DM + db + d16;
    *(us8*)(wt + off)     = *(us8*)&ov[0];
    *(us8*)(wt + off + 8) = *(us8*)&ov[8];
}

// ---------------------------------------------------------------------------
// K1: fused q/k/v per-head projection GEMM, fp16 single-term (round-4 form:
// straight in-loop loads — NO dynamically-indexed register arrays).
// which==2 (V): output transposed via LDS -> vt [H][DK][ROWS].
// ---------------------------------------------------------------------------
__global__ __launch_bounds__(256) void k1_proj_qkv(
    const unsigned short* __restrict__ xh,   // fp16 [3][ROWS][DM]
    const unsigned short* __restrict__ wt,   // fp16 [3][H][DK][DM]
    unsigned short* __restrict__ qh,         // fp16 [H][ROWS][DK]
    unsigned short* __restrict__ kh,         // fp16 [H][ROWS][DK]
    unsigned short* __restrict__ vt)         // fp16 [H][DK][ROWS]
{
    __shared__ unsigned short vtile[64][137];

    int bx = blockIdx.x;
    int which = bx / (H_ * 32);
    int rem   = bx % (H_ * 32);
    int h     = rem & 15;          // h fastest: consecutive blocks share A tile
    int mbase = (rem >> 4) * 128;

    const unsigned short* X = xh + (size_t)which * ROWS * DM;
    const unsigned short* W = wt + ((size_t)which * H_ + h) * DK * DM;

    int wave = threadIdx.x >> 6, lane = threadIdx.x & 63;
    int quad = lane >> 4, l16 = lane & 15;
    int row0 = mbase + wave * 32;

    f32x4 acc[2][4];
    #pragma unroll
    for (int i = 0; i < 2; i++)
        #pragma unroll
        for (int j = 0; j < 4; j++) acc[i][j] = (f32x4)0.0f;

    for (int d = 0; d < DM; d += 32) {
        int koff = d + quad * 8;
        f16x8 a0 = ld8h(X + (size_t)(row0 + l16) * DM + koff);
        f16x8 a1 = ld8h(X + (size_t)(row0 + 16 + l16) * DM + koff);
        #pragma unroll
        for (int nt = 0; nt < 4; nt++) {
            f16x8 bfr = ld8h(W + (size_t)(nt * 16 + l16) * DM + koff);
            acc[0][nt] = MFMA(a0, bfr, acc[0][nt]);
            acc[1][nt] = MFMA(a1, bfr, acc[1][nt]);
        }
    }

    if (which < 2) {
        unsigned short* OUT = ((which == 0) ? qh : kh) + (size_t)h * ROWS * DK;
        #pragma unroll
        for (int mt = 0; mt < 2; mt++)
            #pragma unroll
            for (int nt = 0; nt < 4; nt++)
                #pragma unroll
                for (int r = 0; r < 4; r++) {
                    int row = row0 + mt * 16 + quad * 4 + r;
                    OUT[(size_t)row * DK + nt * 16 + l16] = f2h(acc[mt][nt][r]);
                }
    } else {
        #pragma unroll
        for (int mt = 0; mt < 2; mt++)
            #pragma unroll
            for (int nt = 0; nt < 4; nt++)
                #pragma unroll
                for (int r = 0; r < 4; r++) {
                    int rrel = wave * 32 + mt * 16 + quad * 4 + r;
                    vtile[nt * 16 + l16][rrel] = f2h(acc[mt][nt][r]);
                }
        __syncthreads();
        int t  = threadIdx.x;
        int dk = t >> 2;
        int sg = (t & 3) * 32;
        __align__(16) unsigned short ov[32];
        #pragma unroll
        for (int i = 0; i < 32; i++) ov[i] = vtile[dk][sg + i];
        unsigned short* dp = vt + ((size_t)h * DK + dk) * ROWS + mbase + sg;
        #pragma unroll
        for (int i8 = 0; i8 < 4; i8++)
            *(us8*)(dp + i8 * 8) = *(us8*)&ov[i8 * 8];
    }
}

// ---------------------------------------------------------------------------
// K2: flash attention, S^T orientation (A=K, B=Q) -> cheap per-lane softmax,
// packed b64 P-write, WAR-safe single-buffer prefetch of K and V fragments.
// (All register arrays indexed only by unrolled compile-time constants.)
// ---------------------------------------------------------------------------
__global__ __launch_bounds__(256) void k2_attn(
    const unsigned short* __restrict__ qh,   // fp16 [H][ROWS][DK]
    const unsigned short* __restrict__ kh,   // fp16 [H][ROWS][DK]
    const unsigned short* __restrict__ vt,   // fp16 [H][DK][ROWS]
    unsigned short* __restrict__ x2)         // fp16 [ROWS][DM]
{
    __shared__ __align__(16) unsigned short pld[4][16][80];  // per-wave P tile

    int bx = blockIdx.x;
    int h  = bx >> 6;
    int b  = (bx >> 5) & 1;
    int qt = bx & 31;
    int qbase = qt * 64;

    const unsigned short* qhp = qh + ((size_t)h * ROWS + b * L_) * DK;
    const unsigned short* khp = kh + ((size_t)h * ROWS + b * L_) * DK;
    const unsigned short* vtp = vt + (size_t)h * DK * ROWS + b * L_;

    int wave = threadIdx.x >> 6, lane = threadIdx.x & 63;
    int quad = lane >> 4, l16 = lane & 15;

    int qrow = qbase + wave * 16 + l16;
    f16x8 qb0 = ld8h(qhp + (size_t)qrow * DK + quad * 8);
    f16x8 qb1 = ld8h(qhp + (size_t)qrow * DK + 32 + quad * 8);

    // K fragments (A-operand): lane m=l16 -> key, k=quad*8+j -> d
    f16x8 ka0[4], ka1[4], vb[2][4];
    #pragma unroll
    for (int nt = 0; nt < 4; nt++) {
        const unsigned short* kp = khp + (size_t)(nt * 16 + l16) * DK;
        ka0[nt] = ld8h(kp + quad * 8);
        ka1[nt] = ld8h(kp + 32 + quad * 8);
    }
    #pragma unroll
    for (int kk = 0; kk < 2; kk++)
        #pragma unroll
        for (int nt = 0; nt < 4; nt++)
            vb[kk][nt] = ld8h(vtp + (size_t)(nt * 16 + l16) * ROWS + kk * 32 + quad * 8);

    // per-lane online-softmax stats for COLUMN qrow=l16 (replicated over quads)
    float m_i = -1e30f, l_i = 0.0f;
    f32x4 o[4];
    #pragma unroll
    for (int nt = 0; nt < 4; nt++) o[nt] = (f32x4)0.0f;

    for (int kt = 0; kt < 32; kt++) {
        int kb  = kt * 64;
        int kbn = (kb + 64) & (L_ - 1);   // wrap: last prefetch reads valid junk

        // S^T = K Q^T : s[nt][r] = S[qrow=l16][key = kb + nt*16 + quad*4 + r]
        f32x4 s[4];
        #pragma unroll
        for (int nt = 0; nt < 4; nt++) s[nt] = (f32x4)0.0f;
        #pragma unroll
        for (int nt = 0; nt < 4; nt++) {
            s[nt] = MFMA(ka0[nt], qb0, s[nt]);
            s[nt] = MFMA(ka1[nt], qb1, s[nt]);
        }

        // prefetch K for next tile (WAR-safe: ka just consumed)
        #pragma unroll
        for (int nt = 0; nt < 4; nt++) {
            const unsigned short* kp = khp + (size_t)(kbn + nt * 16 + l16) * DK;
            ka0[nt] = ld8h(kp + quad * 8);
            ka1[nt] = ld8h(kp + 32 + quad * 8);
        }

        // online softmax: local reduce over 16 regs + 2 shuffle steps
        float mx = s[0][0];
        #pragma unroll
        for (int nt = 0; nt < 4; nt++)
            #pragma unroll
            for (int r = 0; r < 4; r++) mx = fmaxf(mx, s[nt][r]);
        mx = fmaxf(mx, __shfl_xor(mx, 16));
        mx = fmaxf(mx, __shfl_xor(mx, 32));
        float mnew  = fmaxf(m_i, mx);
        float alpha = __expf(m_i - mnew);
        float rs = 0.0f;
        #pragma unroll
        for (int nt = 0; nt < 4; nt++)
            #pragma unroll
            for (int r = 0; r < 4; r++) {
                float pv = __expf(s[nt][r] - mnew);
                s[nt][r] = pv;
                rs += pv;
            }
        rs += __shfl_xor(rs, 16);
        rs += __shfl_xor(rs, 32);
        l_i = l_i * alpha + rs;
        m_i = mnew;

        // rescale O: row quad*4+r needs alpha of column quad*4+r
        #pragma unroll
        for (int r = 0; r < 4; r++) {
            float av = __shfl(alpha, quad * 4 + r);
            #pragma unroll
            for (int nt = 0; nt < 4; nt++) o[nt][r] *= av;
        }

        // P -> per-wave LDS: lane owns 4 consecutive keys per nt -> one b64 store
        #pragma unroll
        for (int nt = 0; nt < 4; nt++) {
            us4v pk;
            pk[0] = f2h(s[nt][0]); pk[1] = f2h(s[nt][1]);
            pk[2] = f2h(s[nt][2]); pk[3] = f2h(s[nt][3]);
            *(us4v*)&pld[wave][l16][nt * 16 + quad * 4] = pk;
        }

        // O += P V
        #pragma unroll
        for (int kk = 0; kk < 2; kk++) {
            f16x8 pa = *(const f16x8*)&pld[wave][l16][kk * 32 + quad * 8];
            #pragma unroll
            for (int nt = 0; nt < 4; nt++)
                o[nt] = MFMA(pa, vb[kk][nt], o[nt]);
        }

        // prefetch V for next tile (WAR-safe: vb just consumed)
        #pragma unroll
        for (int kk = 0; kk < 2; kk++)
            #pragma unroll
            for (int nt = 0; nt < 4; nt++)
                vb[kk][nt] = ld8h(vtp + (size_t)(nt * 16 + l16) * ROWS + kbn + kk * 32 + quad * 8);
    }

    // epilogue: /l_i, * qh, head-concat store (fp16)
    float linv = 1.0f / l_i;
    #pragma unroll
    for (int r = 0; r < 4; r++) {
        float lv = __shfl(linv, quad * 4 + r);
        int row = qbase + wave * 16 + quad * 4 + r;
        #pragma unroll
        for (int nt = 0; nt < 4; nt++) {
            int col = nt * 16 + l16;
            float qv = h2f(qhp[(size_t)row * DK + col]);
            float val = o[nt][r] * lv * qv;
            x2[((size_t)b * L_ + row) * DM + h * DK + col] = f2h(val);
        }
    }
}

// ---------------------------------------------------------------------------
// K3: output projection  out = X2 @ w_proj^T + b_proj  (round-4 form)
// ---------------------------------------------------------------------------
__global__ __launch_bounds__(256) void k3_out_proj(
    const unsigned short* __restrict__ x2,     // fp16 [ROWS][DM]
    const unsigned short* __restrict__ wph,    // fp16 [DM][DM] (row = out dim)
    const float* __restrict__ bias,
    float* __restrict__ out)
{
    int bx = blockIdx.x;
    int mt  = bx >> 4;
    int ntb = bx & 15;
    int mbase = mt * 128, nbase = ntb * 64;

    int wave = threadIdx.x >> 6, lane = threadIdx.x & 63;
    int quad = lane >> 4, l16 = lane & 15;
    int row0 = mbase + wave * 32;

    f32x4 acc[2][4];
    #pragma unroll
    for (int i = 0; i < 2; i++)
        #pragma unroll
        for (int j = 0; j < 4; j++) acc[i][j] = (f32x4)0.0f;

    for (int c = 0; c < DM; c += 32) {
        int koff = c + quad * 8;
        f16x8 a0 = ld8h(x2 + (size_t)(row0 + l16) * DM + koff);
        f16x8 a1 = ld8h(x2 + (size_t)(row0 + 16 + l16) * DM + koff);
        #pragma unroll
        for (int nt = 0; nt < 4; nt++) {
            f16x8 bfr = ld8h(wph + (size_t)(nbase + nt * 16 + l16) * DM + koff);
            acc[0][nt] = MFMA(a0, bfr, acc[0][nt]);
            acc[1][nt] = MFMA(a1, bfr, acc[1][nt]);
        }
    }

    #pragma unroll
    for (int mt2 = 0; mt2 < 2; mt2++)
        #pragma unroll
        for (int nt = 0; nt < 4; nt++)
            #pragma unroll
            for (int r = 0; r < 4; r++) {
                int row = row0 + mt2 * 16 + quad * 4 + r;
                int col = nbase + nt * 16 + l16;
                out[(size_t)row * DM + col] = acc[mt2][nt][r] + bias[col];
            }
}

// ---------------------------------------------------------------------------
extern "C" void kernel_launch(void* const* d_in, const int* in_sizes, int n_in,
                              void* d_out, int out_size, void* d_ws, size_t ws_size,
                              hipStream_t stream)
{
    const float* q     = (const float*)d_in[0];
    const float* k     = (const float*)d_in[1];
    const float* v     = (const float*)d_in[2];
    const float* wqs   = (const float*)d_in[3];
    const float* wks   = (const float*)d_in[4];
    const float* wvs   = (const float*)d_in[5];
    const float* wproj = (const float*)d_in[6];
    const float* bproj = (const float*)d_in[7];
    float* out = (float*)d_out;

    char* ws = (char*)d_ws;
    #define MB (size_t)(1024 * 1024)
    unsigned short* xh  = (unsigned short*)(ws);            // 24 MB (3 x 8 MB)
    unsigned short* wt  = (unsigned short*)(ws + 24 * MB);  // 6 MB
    unsigned short* wph = (unsigned short*)(ws + 30 * MB);  // 2 MB
    unsigned short* qh  = (unsigned short*)(ws + 32 * MB);  // 8 MB
    unsigned short* kh  = (unsigned short*)(ws + 40 * MB);  // 8 MB
    unsigned short* vt  = (unsigned short*)(ws + 48 * MB);  // 8 MB
    unsigned short* x2  = (unsigned short*)(ws + 56 * MB);  // 8 MB (total 64 MB)

    kcvt<<<dim3((ROWS * DM) / (256 * 8)), dim3(256), 0, stream>>>(q, xh);
    kcvt<<<dim3((ROWS * DM) / (256 * 8)), dim3(256), 0, stream>>>(k, xh + (size_t)ROWS * DM);
    kcvt<<<dim3((ROWS * DM) / (256 * 8)), dim3(256), 0, stream>>>(v, xh + (size_t)2 * ROWS * DM);
    kcvt<<<dim3((DM * DM) / (256 * 8)), dim3(256), 0, stream>>>(wproj, wph);
    k0_transpose_w<<<dim3(3 * H_ * 16), dim3(256), 0, stream>>>(wqs, wks, wvs, wt);

    k1_proj_qkv<<<dim3(3 * H_ * 32), dim3(256), 0, stream>>>(xh, wt, qh, kh, vt);
    k2_attn<<<dim3(H_ * B_ * 32), dim3(256), 0, stream>>>(qh, kh, vt, x2);
    k3_out_proj<<<dim3((ROWS / 128) * (DM / 64)), dim3(256), 0, stream>>>(x2, wph, bproj, out);
}

// Round 7
// 382.893 us; speedup vs baseline: 30.8576x; 1.4099x over previous
//
#include <hip/hip_runtime.h>

#define B_ 2
#define L_ 2048
#define DM 1024
#define H_ 16
#define DK 64
#define ROWS (B_*L_)   // 4096

typedef _Float16 f16x8 __attribute__((ext_vector_type(8)));
typedef float    f32x4 __attribute__((ext_vector_type(4)));
typedef unsigned short us8 __attribute__((ext_vector_type(8)));
typedef unsigned short us4v __attribute__((ext_vector_type(4)));

__device__ __forceinline__ unsigned short f2h(float f) {
    _Float16 h = (_Float16)f;
    return __builtin_bit_cast(unsigned short, h);
}
__device__ __forceinline__ float h2f(unsigned short u) {
    return (float)__builtin_bit_cast(_Float16, u);
}
__device__ __forceinline__ f16x8 ld8h(const unsigned short* p) {
    return *reinterpret_cast<const f16x8*>(p);
}

#define MFMA(a, b, c) __builtin_amdgcn_mfma_f32_16x16x32_f16((a), (b), (c), 0, 0, 0)

// ---------------------------------------------------------------------------
// kcvt: f32 -> fp16 bulk convert (8 elems/thread)
// ---------------------------------------------------------------------------
__global__ __launch_bounds__(256) void kcvt(
    const float* __restrict__ src, unsigned short* __restrict__ dst)
{
    size_t i = ((size_t)blockIdx.x * 256 + threadIdx.x) * 8;
    const float4* s4 = (const float4*)(src + i);
    float4 a = s4[0], b = s4[1];
    us8 u;
    u[0] = f2h(a.x); u[1] = f2h(a.y); u[2] = f2h(a.z); u[3] = f2h(a.w);
    u[4] = f2h(b.x); u[5] = f2h(b.y); u[6] = f2h(b.z); u[7] = f2h(b.w);
    *(us8*)(dst + i) = u;
}

// ---------------------------------------------------------------------------
// K0: transpose per-head weights (f32) [3][H][DM][DK] -> fp16 [3][H][DK][DM]
// ---------------------------------------------------------------------------
__global__ __launch_bounds__(256) void k0_transpose_w(
    const float* __restrict__ wq,
    const float* __restrict__ wk,
    const float* __restrict__ wv,
    unsigned short* __restrict__ wt)
{
    __shared__ unsigned short tile[64][65];
    int bx = blockIdx.x;
    int which = bx / (H_ * 16);
    int rem   = bx % (H_ * 16);
    int h  = rem >> 4;
    int db = (rem & 15) * 64;
    const float* src = (which == 0) ? wq : (which == 1) ? wk : wv;

    int t = threadIdx.x;
    int r = t >> 2;
    int c = (t & 3) * 16;
    const float4* sp = (const float4*)(src + ((size_t)(h * DM + db + r)) * DK + c);
    #pragma unroll
    for (int i4 = 0; i4 < 4; i4++) {
        float4 f = sp[i4];
        tile[r][c + i4 * 4 + 0] = f2h(f.x);
        tile[r][c + i4 * 4 + 1] = f2h(f.y);
        tile[r][c + i4 * 4 + 2] = f2h(f.z);
        tile[r][c + i4 * 4 + 3] = f2h(f.w);
    }
    __syncthreads();

    int n   = t >> 2;
    int d16 = (t & 3) * 16;
    __align__(16) unsigned short ov[16];
    #pragma unroll
    for (int i = 0; i < 16; i++) ov[i] = tile[d16 + i][n];
    size_t off = (((size_t)which * H_ + h) * DK + n) * DM + db + d16;
    *(us8*)(wt + off)     = *(us8*)&ov[0];
    *(us8*)(wt + off + 8) = *(us8*)&ov[8];
}

// ---------------------------------------------------------------------------
// K1: fused q/k/v per-head projection GEMM (round-4 form, frozen).
// which==2 (V): output transposed via LDS -> vt [H][DK][ROWS].
// ---------------------------------------------------------------------------
__global__ __launch_bounds__(256) void k1_proj_qkv(
    const unsigned short* __restrict__ xh,   // fp16 [3][ROWS][DM]
    const unsigned short* __restrict__ wt,   // fp16 [3][H][DK][DM]
    unsigned short* __restrict__ qh,         // fp16 [H][ROWS][DK]
    unsigned short* __restrict__ kh,         // fp16 [H][ROWS][DK]
    unsigned short* __restrict__ vt)         // fp16 [H][DK][ROWS]
{
    __shared__ unsigned short vtile[64][137];

    int bx = blockIdx.x;
    int which = bx / (H_ * 32);
    int rem   = bx % (H_ * 32);
    int h     = rem & 15;
    int mbase = (rem >> 4) * 128;

    const unsigned short* X = xh + (size_t)which * ROWS * DM;
    const unsigned short* W = wt + ((size_t)which * H_ + h) * DK * DM;

    int wave = threadIdx.x >> 6, lane = threadIdx.x & 63;
    int quad = lane >> 4, l16 = lane & 15;
    int row0 = mbase + wave * 32;

    f32x4 acc[2][4];
    #pragma unroll
    for (int i = 0; i < 2; i++)
        #pragma unroll
        for (int j = 0; j < 4; j++) acc[i][j] = (f32x4)0.0f;

    for (int d = 0; d < DM; d += 32) {
        int koff = d + quad * 8;
        f16x8 a0 = ld8h(X + (size_t)(row0 + l16) * DM + koff);
        f16x8 a1 = ld8h(X + (size_t)(row0 + 16 + l16) * DM + koff);
        #pragma unroll
        for (int nt = 0; nt < 4; nt++) {
            f16x8 bfr = ld8h(W + (size_t)(nt * 16 + l16) * DM + koff);
            acc[0][nt] = MFMA(a0, bfr, acc[0][nt]);
            acc[1][nt] = MFMA(a1, bfr, acc[1][nt]);
        }
    }

    if (which < 2) {
        unsigned short* OUT = ((which == 0) ? qh : kh) + (size_t)h * ROWS * DK;
        #pragma unroll
        for (int mt = 0; mt < 2; mt++)
            #pragma unroll
            for (int nt = 0; nt < 4; nt++)
                #pragma unroll
                for (int r = 0; r < 4; r++) {
                    int row = row0 + mt * 16 + quad * 4 + r;
                    OUT[(size_t)row * DK + nt * 16 + l16] = f2h(acc[mt][nt][r]);
                }
    } else {
        #pragma unroll
        for (int mt = 0; mt < 2; mt++)
            #pragma unroll
            for (int nt = 0; nt < 4; nt++)
                #pragma unroll
                for (int r = 0; r < 4; r++) {
                    int rrel = wave * 32 + mt * 16 + quad * 4 + r;
                    vtile[nt * 16 + l16][rrel] = f2h(acc[mt][nt][r]);
                }
        __syncthreads();
        int t  = threadIdx.x;
        int dk = t >> 2;
        int sg = (t & 3) * 32;
        __align__(16) unsigned short ov[32];
        #pragma unroll
        for (int i = 0; i < 32; i++) ov[i] = vtile[dk][sg + i];
        unsigned short* dp = vt + ((size_t)h * DK + dk) * ROWS + mbase + sg;
        #pragma unroll
        for (int i8 = 0; i8 < 4; i8++)
            *(us8*)(dp + i8 * 8) = *(us8*)&ov[i8 * 8];
    }
}

// ---------------------------------------------------------------------------
// K2: flash attention. XCD-swizzled (h,b) for L2 locality; K/V tiles staged
// cooperatively in padded LDS (coalesced b128, conflict-free frag reads);
// S^T softmax (per-lane stats, 2 shuffle steps); per-wave P round-trip.
// ---------------------------------------------------------------------------
__global__ __launch_bounds__(256) void k2_attn(
    const unsigned short* __restrict__ qh,   // fp16 [H][ROWS][DK]
    const unsigned short* __restrict__ kh,   // fp16 [H][ROWS][DK]
    const unsigned short* __restrict__ vt,   // fp16 [H][DK][ROWS]
    unsigned short* __restrict__ x2)         // fp16 [ROWS][DM]
{
    __shared__ __align__(16) unsigned short ktile[64][72];   // [key][dk]
    __shared__ __align__(16) unsigned short vtile[64][72];   // [dk][key]
    __shared__ __align__(16) unsigned short pld[4][16][72];  // per-wave P

    int bx = blockIdx.x;
    // XCD swizzle: blocks with bx%8==x land on XCD x -> give each XCD a
    // private group of 4 (h,b) pairs so its 4MB L2 holds the 3MB K/V/Q slice.
    int xcd = bx & 7;
    int loc = bx >> 3;                 // 0..127
    int hb  = xcd * 4 + (loc >> 5);    // 0..31
    int qt  = loc & 31;
    int h = hb >> 1, b = hb & 1;
    int qbase = qt * 64;

    const unsigned short* qhp = qh + ((size_t)h * ROWS + b * L_) * DK;
    const unsigned short* khp = kh + ((size_t)h * ROWS + b * L_) * DK;
    const unsigned short* vtp = vt + (size_t)h * DK * ROWS + b * L_;

    int wave = threadIdx.x >> 6, lane = threadIdx.x & 63;
    int quad = lane >> 4, l16 = lane & 15;
    int t = threadIdx.x;

    int qrow = qbase + wave * 16 + l16;
    f16x8 qb0 = ld8h(qhp + (size_t)qrow * DK + quad * 8);
    f16x8 qb1 = ld8h(qhp + (size_t)qrow * DK + 32 + quad * 8);

    // per-lane online-softmax stats for q-row l16 (replicated over quads)
    float m_i = -1e30f, l_i = 0.0f;
    f32x4 o[4];
    #pragma unroll
    for (int nt = 0; nt < 4; nt++) o[nt] = (f32x4)0.0f;

    for (int kt = 0; kt < 32; kt++) {
        int kb = kt * 64;

        // ---- cooperative staging: 8KB K-tile + 8KB V-tile, b128 coalesced
        {
            const unsigned short* kg = khp + (size_t)kb * DK;  // contiguous 8KB
            #pragma unroll
            for (int i = 0; i < 2; i++) {
                int c = i * 256 + t;             // chunk 0..511 (16B each)
                int key = c >> 3, ch = (c & 7) * 8;
                *(us8*)&ktile[key][ch] = *(const us8*)(kg + c * 8);
            }
            #pragma unroll
            for (int i = 0; i < 2; i++) {
                int c = i * 256 + t;
                int dk = c >> 3, ch = (c & 7) * 8;
                *(us8*)&vtile[dk][ch] = *(const us8*)(vtp + (size_t)dk * ROWS + kb + ch);
            }
        }
        __syncthreads();

        // ---- S^T = K Q^T : s[nt][r] = S[qrow=l16][key = kb + nt*16 + quad*4 + r]
        f32x4 s[4];
        #pragma unroll
        for (int nt = 0; nt < 4; nt++) s[nt] = (f32x4)0.0f;
        #pragma unroll
        for (int nt = 0; nt < 4; nt++) {
            f16x8 ka0 = *(const f16x8*)&ktile[nt * 16 + l16][quad * 8];
            f16x8 ka1 = *(const f16x8*)&ktile[nt * 16 + l16][32 + quad * 8];
            s[nt] = MFMA(ka0, qb0, s[nt]);
            s[nt] = MFMA(ka1, qb1, s[nt]);
        }

        // ---- online softmax: local reduce over 16 regs + 2 shuffle steps
        float mx = s[0][0];
        #pragma unroll
        for (int nt = 0; nt < 4; nt++)
            #pragma unroll
            for (int r = 0; r < 4; r++) mx = fmaxf(mx, s[nt][r]);
        mx = fmaxf(mx, __shfl_xor(mx, 16));
        mx = fmaxf(mx, __shfl_xor(mx, 32));
        float mnew  = fmaxf(m_i, mx);
        float alpha = __expf(m_i - mnew);
        float rs = 0.0f;
        #pragma unroll
        for (int nt = 0; nt < 4; nt++)
            #pragma unroll
            for (int r = 0; r < 4; r++) {
                float pv = __expf(s[nt][r] - mnew);
                s[nt][r] = pv;
                rs += pv;
            }
        rs += __shfl_xor(rs, 16);
        rs += __shfl_xor(rs, 32);
        l_i = l_i * alpha + rs;
        m_i = mnew;

        // rescale O: row quad*4+r needs alpha of q-row quad*4+r
        #pragma unroll
        for (int r = 0; r < 4; r++) {
            float av = __shfl(alpha, quad * 4 + r);
            #pragma unroll
            for (int nt = 0; nt < 4; nt++) o[nt][r] *= av;
        }

        // ---- P -> per-wave LDS (one b64/lane per nt), no barrier needed
        #pragma unroll
        for (int nt = 0; nt < 4; nt++) {
            us4v pk;
            pk[0] = f2h(s[nt][0]); pk[1] = f2h(s[nt][1]);
            pk[2] = f2h(s[nt][2]); pk[3] = f2h(s[nt][3]);
            *(us4v*)&pld[wave][l16][nt * 16 + quad * 4] = pk;
        }

        // ---- O += P V (V frags from LDS tile)
        #pragma unroll
        for (int kk = 0; kk < 2; kk++) {
            f16x8 pa = *(const f16x8*)&pld[wave][l16][kk * 32 + quad * 8];
            #pragma unroll
            for (int nt = 0; nt < 4; nt++) {
                f16x8 vb = *(const f16x8*)&vtile[nt * 16 + l16][kk * 32 + quad * 8];
                o[nt] = MFMA(pa, vb, o[nt]);
            }
        }
        __syncthreads();   // protect ktile/vtile before next stage
    }

    // epilogue: /l_i, * qh, head-concat store (fp16)
    float linv = 1.0f / l_i;
    #pragma unroll
    for (int r = 0; r < 4; r++) {
        float lv = __shfl(linv, quad * 4 + r);
        int row = qbase + wave * 16 + quad * 4 + r;
        #pragma unroll
        for (int nt = 0; nt < 4; nt++) {
            int col = nt * 16 + l16;
            float qv = h2f(qhp[(size_t)row * DK + col]);
            float val = o[nt][r] * lv * qv;
            x2[((size_t)b * L_ + row) * DM + h * DK + col] = f2h(val);
        }
    }
}

// ---------------------------------------------------------------------------
// K3: output projection  out = X2 @ w_proj^T + b_proj  (round-4 form, frozen)
// ---------------------------------------------------------------------------
__global__ __launch_bounds__(256) void k3_out_proj(
    const unsigned short* __restrict__ x2,     // fp16 [ROWS][DM]
    const unsigned short* __restrict__ wph,    // fp16 [DM][DM] (row = out dim)
    const float* __restrict__ bias,
    float* __restrict__ out)
{
    int bx = blockIdx.x;
    int mt  = bx >> 4;
    int ntb = bx & 15;
    int mbase = mt * 128, nbase = ntb * 64;

    int wave = threadIdx.x >> 6, lane = threadIdx.x & 63;
    int quad = lane >> 4, l16 = lane & 15;
    int row0 = mbase + wave * 32;

    f32x4 acc[2][4];
    #pragma unroll
    for (int i = 0; i < 2; i++)
        #pragma unroll
        for (int j = 0; j < 4; j++) acc[i][j] = (f32x4)0.0f;

    for (int c = 0; c < DM; c += 32) {
        int koff = c + quad * 8;
        f16x8 a0 = ld8h(x2 + (size_t)(row0 + l16) * DM + koff);
        f16x8 a1 = ld8h(x2 + (size_t)(row0 + 16 + l16) * DM + koff);
        #pragma unroll
        for (int nt = 0; nt < 4; nt++) {
            f16x8 bfr = ld8h(wph + (size_t)(nbase + nt * 16 + l16) * DM + koff);
            acc[0][nt] = MFMA(a0, bfr, acc[0][nt]);
            acc[1][nt] = MFMA(a1, bfr, acc[1][nt]);
        }
    }

    #pragma unroll
    for (int mt2 = 0; mt2 < 2; mt2++)
        #pragma unroll
        for (int nt = 0; nt < 4; nt++)
            #pragma unroll
            for (int r = 0; r < 4; r++) {
                int row = row0 + mt2 * 16 + quad * 4 + r;
                int col = nbase + nt * 16 + l16;
                out[(size_t)row * DM + col] = acc[mt2][nt][r] + bias[col];
            }
}

// ---------------------------------------------------------------------------
extern "C" void kernel_launch(void* const* d_in, const int* in_sizes, int n_in,
                              void* d_out, int out_size, void* d_ws, size_t ws_size,
                              hipStream_t stream)
{
    const float* q     = (const float*)d_in[0];
    const float* k     = (const float*)d_in[1];
    const float* v     = (const float*)d_in[2];
    const float* wqs   = (const float*)d_in[3];
    const float* wks   = (const float*)d_in[4];
    const float* wvs   = (const float*)d_in[5];
    const float* wproj = (const float*)d_in[6];
    const float* bproj = (const float*)d_in[7];
    float* out = (float*)d_out;

    char* ws = (char*)d_ws;
    #define MB (size_t)(1024 * 1024)
    unsigned short* xh  = (unsigned short*)(ws);            // 24 MB (3 x 8 MB)
    unsigned short* wt  = (unsigned short*)(ws + 24 * MB);  // 6 MB
    unsigned short* wph = (unsigned short*)(ws + 30 * MB);  // 2 MB
    unsigned short* qh  = (unsigned short*)(ws + 32 * MB);  // 8 MB
    unsigned short* kh  = (unsigned short*)(ws + 40 * MB);  // 8 MB
    unsigned short* vt  = (unsigned short*)(ws + 48 * MB);  // 8 MB
    unsigned short* x2  = (unsigned short*)(ws + 56 * MB);  // 8 MB (total 64 MB)

    kcvt<<<dim3((ROWS * DM) / (256 * 8)), dim3(256), 0, stream>>>(q, xh);
    kcvt<<<dim3((ROWS * DM) / (256 * 8)), dim3(256), 0, stream>>>(k, xh + (size_t)ROWS * DM);
    kcvt<<<dim3((ROWS * DM) / (256 * 8)), dim3(256), 0, stream>>>(v, xh + (size_t)2 * ROWS * DM);
    kcvt<<<dim3((DM * DM) / (256 * 8)), dim3(256), 0, stream>>>(wproj, wph);
    k0_transpose_w<<<dim3(3 * H_ * 16), dim3(256), 0, stream>>>(wqs, wks, wvs, wt);

    k1_proj_qkv<<<dim3(3 * H_ * 32), dim3(256), 0, stream>>>(xh, wt, qh, kh, vt);
    k2_attn<<<dim3(H_ * B_ * 32), dim3(256), 0, stream>>>(qh, kh, vt, x2);
    k3_out_proj<<<dim3((ROWS / 128) * (DM / 64)), dim3(256), 0, stream>>>(x2, wph, bproj, out);
}

// Round 8
// 281.875 us; speedup vs baseline: 41.9162x; 1.3584x over previous
//
#include <hip/hip_runtime.h>

#define B_ 2
#define L_ 2048
#define DM 1024
#define H_ 16
#define DK 64
#define ROWS (B_*L_)   // 4096
#define BK 32
#define LDT 40         // LDS tile row stride (elems): 80B, 16B-aligned, ~2-way banks

typedef _Float16 f16x8 __attribute__((ext_vector_type(8)));
typedef float    f32x4 __attribute__((ext_vector_type(4)));
typedef unsigned short us8 __attribute__((ext_vector_type(8)));
typedef unsigned short us4v __attribute__((ext_vector_type(4)));

__device__ __forceinline__ unsigned short f2h(float f) {
    _Float16 h = (_Float16)f;
    return __builtin_bit_cast(unsigned short, h);
}
__device__ __forceinline__ float h2f(unsigned short u) {
    return (float)__builtin_bit_cast(_Float16, u);
}
__device__ __forceinline__ f16x8 ld8h(const unsigned short* p) {
    return *reinterpret_cast<const f16x8*>(p);
}

#define MFMA(a, b, c) __builtin_amdgcn_mfma_f32_16x16x32_f16((a), (b), (c), 0, 0, 0)

// ---------------------------------------------------------------------------
// kcvt: f32 -> fp16 bulk convert (8 elems/thread)
// ---------------------------------------------------------------------------
__global__ __launch_bounds__(256) void kcvt(
    const float* __restrict__ src, unsigned short* __restrict__ dst)
{
    size_t i = ((size_t)blockIdx.x * 256 + threadIdx.x) * 8;
    const float4* s4 = (const float4*)(src + i);
    float4 a = s4[0], b = s4[1];
    us8 u;
    u[0] = f2h(a.x); u[1] = f2h(a.y); u[2] = f2h(a.z); u[3] = f2h(a.w);
    u[4] = f2h(b.x); u[5] = f2h(b.y); u[6] = f2h(b.z); u[7] = f2h(b.w);
    *(us8*)(dst + i) = u;
}

// ---------------------------------------------------------------------------
// K0: transpose per-head weights (f32) [3][H][DM][DK] -> fp16 [3][H][DK][DM]
// (result is an n-major [3][n=h*64+dk][d] B^T operand for the fused GEMM)
// ---------------------------------------------------------------------------
__global__ __launch_bounds__(256) void k0_transpose_w(
    const float* __restrict__ wq,
    const float* __restrict__ wk,
    const float* __restrict__ wv,
    unsigned short* __restrict__ wt)
{
    __shared__ unsigned short tile[64][65];
    int bx = blockIdx.x;
    int which = bx / (H_ * 16);
    int rem   = bx % (H_ * 16);
    int h  = rem >> 4;
    int db = (rem & 15) * 64;
    const float* src = (which == 0) ? wq : (which == 1) ? wk : wv;

    int t = threadIdx.x;
    int r = t >> 2;
    int c = (t & 3) * 16;
    const float4* sp = (const float4*)(src + ((size_t)(h * DM + db + r)) * DK + c);
    #pragma unroll
    for (int i4 = 0; i4 < 4; i4++) {
        float4 f = sp[i4];
        tile[r][c + i4 * 4 + 0] = f2h(f.x);
        tile[r][c + i4 * 4 + 1] = f2h(f.y);
        tile[r][c + i4 * 4 + 2] = f2h(f.z);
        tile[r][c + i4 * 4 + 3] = f2h(f.w);
    }
    __syncthreads();

    int n   = t >> 2;
    int d16 = (t & 3) * 16;
    __align__(16) unsigned short ov[16];
    #pragma unroll
    for (int i = 0; i < 16; i++) ov[i] = tile[d16 + i][n];
    size_t off = (((size_t)which * H_ + h) * DK + n) * DM + db + d16;
    *(us8*)(wt + off)     = *(us8*)&ov[0];
    *(us8*)(wt + off + 8) = *(us8*)&ov[8];
}

// ---------------------------------------------------------------------------
// K1: fused QKV projection as 3x [4096x1024]@[1024x1024]^T staged GEMM.
// 128x128 tile/block, BK=32, register-double-buffered LDS staging.
// Waves: 2x2 grid, each 64x64 (4x4 MFMA tiles). which==2 writes V transposed.
// ---------------------------------------------------------------------------
__global__ __launch_bounds__(256) void k1_proj_qkv(
    const unsigned short* __restrict__ xh,   // fp16 [3][ROWS][DM]
    const unsigned short* __restrict__ wt,   // fp16 [3][1024 n][1024 d]
    unsigned short* __restrict__ qh,         // fp16 [H][ROWS][DK]
    unsigned short* __restrict__ kh,         // fp16 [H][ROWS][DK]
    unsigned short* __restrict__ vt)         // fp16 [H][DK][ROWS]
{
    __shared__ __align__(16) unsigned short sA[128 * LDT];
    __shared__ __align__(16) unsigned short sB[128 * LDT];

    int bx = blockIdx.x;
    int which = bx >> 8;           // 0..2
    int rem   = bx & 255;
    int mbase = (rem >> 3) * 128;  // 32 m-tiles
    int nbase = (rem & 7) * 128;   // 8 n-tiles

    const unsigned short* Ag = xh + (size_t)which * ROWS * DM;
    const unsigned short* Bg = wt + (size_t)which * DM * DM;

    int t = threadIdx.x;
    int wave = t >> 6, lane = t & 63, quad = lane >> 4, l16 = lane & 15;
    int wm = (wave >> 1) * 64, wn = (wave & 1) * 64;

    // staging map: thread covers 16B chunks t and 256+t (global-coalesced)
    int ar0 = t >> 2,          ac0 = t & 3;
    int ar1 = (256 + t) >> 2,  ac1 = t & 3;   // (256+t)&3 == t&3
    const unsigned short* pA0 = Ag + (size_t)(mbase + ar0) * DM + ac0 * 8;
    const unsigned short* pA1 = Ag + (size_t)(mbase + ar1) * DM + ac1 * 8;
    const unsigned short* pB0 = Bg + (size_t)(nbase + ar0) * DM + ac0 * 8;
    const unsigned short* pB1 = Bg + (size_t)(nbase + ar1) * DM + ac1 * 8;
    unsigned short* wA0 = &sA[ar0 * LDT + ac0 * 8];
    unsigned short* wA1 = &sA[ar1 * LDT + ac1 * 8];
    unsigned short* wB0 = &sB[ar0 * LDT + ac0 * 8];
    unsigned short* wB1 = &sB[ar1 * LDT + ac1 * 8];

    f32x4 acc[4][4];
    #pragma unroll
    for (int mi = 0; mi < 4; mi++)
        #pragma unroll
        for (int ni = 0; ni < 4; ni++) acc[mi][ni] = (f32x4)0.0f;

    us8 rA0 = *(const us8*)pA0, rA1 = *(const us8*)pA1;
    us8 rB0 = *(const us8*)pB0, rB1 = *(const us8*)pB1;

    for (int step = 0; step < 32; step++) {
        if (step) __syncthreads();          // prior frag reads done
        *(us8*)wA0 = rA0; *(us8*)wA1 = rA1;
        *(us8*)wB0 = rB0; *(us8*)wB1 = rB1;
        __syncthreads();
        if (step < 31) {                    // prefetch next K-slice
            pA0 += BK; pA1 += BK; pB0 += BK; pB1 += BK;
            rA0 = *(const us8*)pA0; rA1 = *(const us8*)pA1;
            rB0 = *(const us8*)pB0; rB1 = *(const us8*)pB1;
        }
        f16x8 aF[4], bF[4];
        #pragma unroll
        for (int mi = 0; mi < 4; mi++)
            aF[mi] = *(const f16x8*)&sA[(wm + mi * 16 + l16) * LDT + quad * 8];
        #pragma unroll
        for (int ni = 0; ni < 4; ni++)
            bF[ni] = *(const f16x8*)&sB[(wn + ni * 16 + l16) * LDT + quad * 8];
        #pragma unroll
        for (int mi = 0; mi < 4; mi++)
            #pragma unroll
            for (int ni = 0; ni < 4; ni++)
                acc[mi][ni] = MFMA(aF[mi], bF[ni], acc[mi][ni]);
    }

    int h = (nbase >> 6) + (wave & 1);      // wave's 64-col span = one head
    if (which < 2) {
        unsigned short* OUT = ((which == 0) ? qh : kh) + (size_t)h * ROWS * DK;
        #pragma unroll
        for (int mi = 0; mi < 4; mi++)
            #pragma unroll
            for (int ni = 0; ni < 4; ni++)
                #pragma unroll
                for (int r = 0; r < 4; r++) {
                    int row = mbase + wm + mi * 16 + quad * 4 + r;
                    OUT[(size_t)row * DK + ni * 16 + l16] = f2h(acc[mi][ni][r]);
                }
    } else {
        // V transposed: vt[h][dk][row]; lane owns 4 consecutive rows -> 8B store
        unsigned short* OUT = vt + (size_t)h * DK * ROWS;
        #pragma unroll
        for (int mi = 0; mi < 4; mi++)
            #pragma unroll
            for (int ni = 0; ni < 4; ni++) {
                int dk   = ni * 16 + l16;
                int rowb = mbase + wm + mi * 16 + quad * 4;
                us4v pk;
                pk[0] = f2h(acc[mi][ni][0]); pk[1] = f2h(acc[mi][ni][1]);
                pk[2] = f2h(acc[mi][ni][2]); pk[3] = f2h(acc[mi][ni][3]);
                *(us4v*)(OUT + (size_t)dk * ROWS + rowb) = pk;
            }
    }
}

// ---------------------------------------------------------------------------
// K2: flash attention (round-7 form, frozen). XCD-swizzled, LDS-staged K/V,
// S^T softmax, per-wave P round-trip.
// ---------------------------------------------------------------------------
__global__ __launch_bounds__(256) void k2_attn(
    const unsigned short* __restrict__ qh,   // fp16 [H][ROWS][DK]
    const unsigned short* __restrict__ kh,   // fp16 [H][ROWS][DK]
    const unsigned short* __restrict__ vt,   // fp16 [H][DK][ROWS]
    unsigned short* __restrict__ x2)         // fp16 [ROWS][DM]
{
    __shared__ __align__(16) unsigned short ktile[64][72];
    __shared__ __align__(16) unsigned short vtile[64][72];
    __shared__ __align__(16) unsigned short pld[4][16][72];

    int bx = blockIdx.x;
    int xcd = bx & 7;
    int loc = bx >> 3;
    int hb  = xcd * 4 + (loc >> 5);
    int qt  = loc & 31;
    int h = hb >> 1, b = hb & 1;
    int qbase = qt * 64;

    const unsigned short* qhp = qh + ((size_t)h * ROWS + b * L_) * DK;
    const unsigned short* khp = kh + ((size_t)h * ROWS + b * L_) * DK;
    const unsigned short* vtp = vt + (size_t)h * DK * ROWS + b * L_;

    int wave = threadIdx.x >> 6, lane = threadIdx.x & 63;
    int quad = lane >> 4, l16 = lane & 15;
    int t = threadIdx.x;

    int qrow = qbase + wave * 16 + l16;
    f16x8 qb0 = ld8h(qhp + (size_t)qrow * DK + quad * 8);
    f16x8 qb1 = ld8h(qhp + (size_t)qrow * DK + 32 + quad * 8);

    float m_i = -1e30f, l_i = 0.0f;
    f32x4 o[4];
    #pragma unroll
    for (int nt = 0; nt < 4; nt++) o[nt] = (f32x4)0.0f;

    for (int kt = 0; kt < 32; kt++) {
        int kb = kt * 64;
        {
            const unsigned short* kg = khp + (size_t)kb * DK;
            #pragma unroll
            for (int i = 0; i < 2; i++) {
                int c = i * 256 + t;
                int key = c >> 3, ch = (c & 7) * 8;
                *(us8*)&ktile[key][ch] = *(const us8*)(kg + c * 8);
            }
            #pragma unroll
            for (int i = 0; i < 2; i++) {
                int c = i * 256 + t;
                int dk = c >> 3, ch = (c & 7) * 8;
                *(us8*)&vtile[dk][ch] = *(const us8*)(vtp + (size_t)dk * ROWS + kb + ch);
            }
        }
        __syncthreads();

        f32x4 s[4];
        #pragma unroll
        for (int nt = 0; nt < 4; nt++) s[nt] = (f32x4)0.0f;
        #pragma unroll
        for (int nt = 0; nt < 4; nt++) {
            f16x8 ka0 = *(const f16x8*)&ktile[nt * 16 + l16][quad * 8];
            f16x8 ka1 = *(const f16x8*)&ktile[nt * 16 + l16][32 + quad * 8];
            s[nt] = MFMA(ka0, qb0, s[nt]);
            s[nt] = MFMA(ka1, qb1, s[nt]);
        }

        float mx = s[0][0];
        #pragma unroll
        for (int nt = 0; nt < 4; nt++)
            #pragma unroll
            for (int r = 0; r < 4; r++) mx = fmaxf(mx, s[nt][r]);
        mx = fmaxf(mx, __shfl_xor(mx, 16));
        mx = fmaxf(mx, __shfl_xor(mx, 32));
        float mnew  = fmaxf(m_i, mx);
        float alpha = __expf(m_i - mnew);
        float rs = 0.0f;
        #pragma unroll
        for (int nt = 0; nt < 4; nt++)
            #pragma unroll
            for (int r = 0; r < 4; r++) {
                float pv = __expf(s[nt][r] - mnew);
                s[nt][r] = pv;
                rs += pv;
            }
        rs += __shfl_xor(rs, 16);
        rs += __shfl_xor(rs, 32);
        l_i = l_i * alpha + rs;
        m_i = mnew;

        #pragma unroll
        for (int r = 0; r < 4; r++) {
            float av = __shfl(alpha, quad * 4 + r);
            #pragma unroll
            for (int nt = 0; nt < 4; nt++) o[nt][r] *= av;
        }

        #pragma unroll
        for (int nt = 0; nt < 4; nt++) {
            us4v pk;
            pk[0] = f2h(s[nt][0]); pk[1] = f2h(s[nt][1]);
            pk[2] = f2h(s[nt][2]); pk[3] = f2h(s[nt][3]);
            *(us4v*)&pld[wave][l16][nt * 16 + quad * 4] = pk;
        }

        #pragma unroll
        for (int kk = 0; kk < 2; kk++) {
            f16x8 pa = *(const f16x8*)&pld[wave][l16][kk * 32 + quad * 8];
            #pragma unroll
            for (int nt = 0; nt < 4; nt++) {
                f16x8 vb = *(const f16x8*)&vtile[nt * 16 + l16][kk * 32 + quad * 8];
                o[nt] = MFMA(pa, vb, o[nt]);
            }
        }
        __syncthreads();
    }

    float linv = 1.0f / l_i;
    #pragma unroll
    for (int r = 0; r < 4; r++) {
        float lv = __shfl(linv, quad * 4 + r);
        int row = qbase + wave * 16 + quad * 4 + r;
        #pragma unroll
        for (int nt = 0; nt < 4; nt++) {
            int col = nt * 16 + l16;
            float qv = h2f(qhp[(size_t)row * DK + col]);
            float val = o[nt][r] * lv * qv;
            x2[((size_t)b * L_ + row) * DM + h * DK + col] = f2h(val);
        }
    }
}

// ---------------------------------------------------------------------------
// K3: output projection  out = X2 @ w_proj^T + b_proj  (round-4 form, frozen)
// ---------------------------------------------------------------------------
__global__ __launch_bounds__(256) void k3_out_proj(
    const unsigned short* __restrict__ x2,     // fp16 [ROWS][DM]
    const unsigned short* __restrict__ wph,    // fp16 [DM][DM] (row = out dim)
    const float* __restrict__ bias,
    float* __restrict__ out)
{
    int bx = blockIdx.x;
    int mt  = bx >> 4;
    int ntb = bx & 15;
    int mbase = mt * 128, nbase = ntb * 64;

    int wave = threadIdx.x >> 6, lane = threadIdx.x & 63;
    int quad = lane >> 4, l16 = lane & 15;
    int row0 = mbase + wave * 32;

    f32x4 acc[2][4];
    #pragma unroll
    for (int i = 0; i < 2; i++)
        #pragma unroll
        for (int j = 0; j < 4; j++) acc[i][j] = (f32x4)0.0f;

    for (int c = 0; c < DM; c += 32) {
        int koff = c + quad * 8;
        f16x8 a0 = ld8h(x2 + (size_t)(row0 + l16) * DM + koff);
        f16x8 a1 = ld8h(x2 + (size_t)(row0 + 16 + l16) * DM + koff);
        #pragma unroll
        for (int nt = 0; nt < 4; nt++) {
            f16x8 bfr = ld8h(wph + (size_t)(nbase + nt * 16 + l16) * DM + koff);
            acc[0][nt] = MFMA(a0, bfr, acc[0][nt]);
            acc[1][nt] = MFMA(a1, bfr, acc[1][nt]);
        }
    }

    #pragma unroll
    for (int mt2 = 0; mt2 < 2; mt2++)
        #pragma unroll
        for (int nt = 0; nt < 4; nt++)
            #pragma unroll
            for (int r = 0; r < 4; r++) {
                int row = row0 + mt2 * 16 + quad * 4 + r;
                int col = nbase + nt * 16 + l16;
                out[(size_t)row * DM + col] = acc[mt2][nt][r] + bias[col];
            }
}

// ---------------------------------------------------------------------------
extern "C" void kernel_launch(void* const* d_in, const int* in_sizes, int n_in,
                              void* d_out, int out_size, void* d_ws, size_t ws_size,
                              hipStream_t stream)
{
    const float* q     = (const float*)d_in[0];
    const float* k     = (const float*)d_in[1];
    const float* v     = (const float*)d_in[2];
    const float* wqs   = (const float*)d_in[3];
    const float* wks   = (const float*)d_in[4];
    const float* wvs   = (const float*)d_in[5];
    const float* wproj = (const float*)d_in[6];
    const float* bproj = (const float*)d_in[7];
    float* out = (float*)d_out;

    char* ws = (char*)d_ws;
    #define MB (size_t)(1024 * 1024)
    unsigned short* xh  = (unsigned short*)(ws);            // 24 MB (3 x 8 MB)
    unsigned short* wt  = (unsigned short*)(ws + 24 * MB);  // 6 MB
    unsigned short* wph = (unsigned short*)(ws + 30 * MB);  // 2 MB
    unsigned short* qh  = (unsigned short*)(ws + 32 * MB);  // 8 MB
    unsigned short* kh  = (unsigned short*)(ws + 40 * MB);  // 8 MB
    unsigned short* vt  = (unsigned short*)(ws + 48 * MB);  // 8 MB
    unsigned short* x2  = (unsigned short*)(ws + 56 * MB);  // 8 MB (total 64 MB)

    kcvt<<<dim3((ROWS * DM) / (256 * 8)), dim3(256), 0, stream>>>(q, xh);
    kcvt<<<dim3((ROWS * DM) / (256 * 8)), dim3(256), 0, stream>>>(k, xh + (size_t)ROWS * DM);
    kcvt<<<dim3((ROWS * DM) / (256 * 8)), dim3(256), 0, stream>>>(v, xh + (size_t)2 * ROWS * DM);
    kcvt<<<dim3((DM * DM) / (256 * 8)), dim3(256), 0, stream>>>(wproj, wph);
    k0_transpose_w<<<dim3(3 * H_ * 16), dim3(256), 0, stream>>>(wqs, wks, wvs, wt);

    k1_proj_qkv<<<dim3(3 * 32 * 8), dim3(256), 0, stream>>>(xh, wt, qh, kh, vt);
    k2_attn<<<dim3(H_ * B_ * 32), dim3(256), 0, stream>>>(qh, kh, vt, x2);
    k3_out_proj<<<dim3((ROWS / 128) * (DM / 64)), dim3(256), 0, stream>>>(x2, wph, bproj, out);
}

// Round 9
// 262.629 us; speedup vs baseline: 44.9880x; 1.0733x over previous
//
#include <hip/hip_runtime.h>

#define B_ 2
#define L_ 2048
#define DM 1024
#define H_ 16
#define DK 64
#define ROWS (B_*L_)   // 4096
#define BK 32
#define LDT 40         // LDS tile row stride (elems): 80B, 16B-aligned, 2-way banks (free)

typedef _Float16 f16x8 __attribute__((ext_vector_type(8)));
typedef float    f32x4 __attribute__((ext_vector_type(4)));
typedef unsigned short us8 __attribute__((ext_vector_type(8)));
typedef unsigned short us4v __attribute__((ext_vector_type(4)));

__device__ __forceinline__ unsigned short f2h(float f) {
    _Float16 h = (_Float16)f;
    return __builtin_bit_cast(unsigned short, h);
}
__device__ __forceinline__ float h2f(unsigned short u) {
    return (float)__builtin_bit_cast(_Float16, u);
}
__device__ __forceinline__ f16x8 ld8h(const unsigned short* p) {
    return *reinterpret_cast<const f16x8*>(p);
}
__device__ __forceinline__ us8 cvt_us8(float4 a, float4 b) {
    us8 u;
    u[0] = f2h(a.x); u[1] = f2h(a.y); u[2] = f2h(a.z); u[3] = f2h(a.w);
    u[4] = f2h(b.x); u[5] = f2h(b.y); u[6] = f2h(b.z); u[7] = f2h(b.w);
    return u;
}

#define MFMA(a, b, c) __builtin_amdgcn_mfma_f32_16x16x32_f16((a), (b), (c), 0, 0, 0)

// ---------------------------------------------------------------------------
// kcvt: f32 -> fp16 bulk convert (w_proj only now)
// ---------------------------------------------------------------------------
__global__ __launch_bounds__(256) void kcvt(
    const float* __restrict__ src, unsigned short* __restrict__ dst)
{
    size_t i = ((size_t)blockIdx.x * 256 + threadIdx.x) * 8;
    const float4* s4 = (const float4*)(src + i);
    *(us8*)(dst + i) = cvt_us8(s4[0], s4[1]);
}

// ---------------------------------------------------------------------------
// K0: transpose per-head weights (f32) [3][H][DM][DK] -> fp16 [3][H][DK][DM]
// (result is an n-major [3][n=h*64+dk][d] B^T operand for the fused GEMM)
// ---------------------------------------------------------------------------
__global__ __launch_bounds__(256) void k0_transpose_w(
    const float* __restrict__ wq,
    const float* __restrict__ wk,
    const float* __restrict__ wv,
    unsigned short* __restrict__ wt)
{
    __shared__ unsigned short tile[64][65];
    int bx = blockIdx.x;
    int which = bx / (H_ * 16);
    int rem   = bx % (H_ * 16);
    int h  = rem >> 4;
    int db = (rem & 15) * 64;
    const float* src = (which == 0) ? wq : (which == 1) ? wk : wv;

    int t = threadIdx.x;
    int r = t >> 2;
    int c = (t & 3) * 16;
    const float4* sp = (const float4*)(src + ((size_t)(h * DM + db + r)) * DK + c);
    #pragma unroll
    for (int i4 = 0; i4 < 4; i4++) {
        float4 f = sp[i4];
        tile[r][c + i4 * 4 + 0] = f2h(f.x);
        tile[r][c + i4 * 4 + 1] = f2h(f.y);
        tile[r][c + i4 * 4 + 2] = f2h(f.z);
        tile[r][c + i4 * 4 + 3] = f2h(f.w);
    }
    __syncthreads();

    int n   = t >> 2;
    int d16 = (t & 3) * 16;
    __align__(16) unsigned short ov[16];
    #pragma unroll
    for (int i = 0; i < 16; i++) ov[i] = tile[d16 + i][n];
    size_t off = (((size_t)which * H_ + h) * DK + n) * DM + db + d16;
    *(us8*)(wt + off)     = *(us8*)&ov[0];
    *(us8*)(wt + off + 8) = *(us8*)&ov[8];
}

// ---------------------------------------------------------------------------
// K1: fused QKV projection as 3x [4096x1024]@[1024x1024]^T staged GEMM.
// A is read as f32 and converted to fp16 in-register during staging
// (kcvt folded). 128x128 tile, BK=32, register-double-buffered staging.
// which==2 writes V transposed (vt[h][dk][row]).
// ---------------------------------------------------------------------------
__global__ __launch_bounds__(256) void k1_proj_qkv(
    const float* __restrict__ q,
    const float* __restrict__ k,
    const float* __restrict__ v,
    const unsigned short* __restrict__ wt,   // fp16 [3][1024 n][1024 d]
    unsigned short* __restrict__ qh,         // fp16 [H][ROWS][DK]
    unsigned short* __restrict__ kh,         // fp16 [H][ROWS][DK]
    unsigned short* __restrict__ vt)         // fp16 [H][DK][ROWS]
{
    __shared__ __align__(16) unsigned short sA[128 * LDT];
    __shared__ __align__(16) unsigned short sB[128 * LDT];

    int bx = blockIdx.x;
    int which = bx >> 8;           // 0..2
    int rem   = bx & 255;
    int mbase = (rem >> 3) * 128;  // 32 m-tiles
    int nbase = (rem & 7) * 128;   // 8 n-tiles

    const float* Ag = (which == 0) ? q : (which == 1) ? k : v;
    const unsigned short* Bg = wt + (size_t)which * DM * DM;

    int t = threadIdx.x;
    int wave = t >> 6, lane = t & 63, quad = lane >> 4, l16 = lane & 15;
    int wm = (wave >> 1) * 64, wn = (wave & 1) * 64;

    // staging map: thread covers 8-elem chunks t and 256+t (global-coalesced)
    int ar0 = t >> 2,         ac0 = t & 3;
    int ar1 = (256 + t) >> 2, ac1 = t & 3;
    const float* pA0 = Ag + (size_t)(mbase + ar0) * DM + ac0 * 8;   // 2x float4
    const float* pA1 = Ag + (size_t)(mbase + ar1) * DM + ac1 * 8;
    const unsigned short* pB0 = Bg + (size_t)(nbase + ar0) * DM + ac0 * 8;
    const unsigned short* pB1 = Bg + (size_t)(nbase + ar1) * DM + ac1 * 8;
    unsigned short* wA0 = &sA[ar0 * LDT + ac0 * 8];
    unsigned short* wA1 = &sA[ar1 * LDT + ac1 * 8];
    unsigned short* wB0 = &sB[ar0 * LDT + ac0 * 8];
    unsigned short* wB1 = &sB[ar1 * LDT + ac1 * 8];

    f32x4 acc[4][4];
    #pragma unroll
    for (int mi = 0; mi < 4; mi++)
        #pragma unroll
        for (int ni = 0; ni < 4; ni++) acc[mi][ni] = (f32x4)0.0f;

    float4 rA0a = *(const float4*)pA0, rA0b = *(const float4*)(pA0 + 4);
    float4 rA1a = *(const float4*)pA1, rA1b = *(const float4*)(pA1 + 4);
    us8 rB0 = *(const us8*)pB0, rB1 = *(const us8*)pB1;

    for (int step = 0; step < 32; step++) {
        if (step) __syncthreads();          // prior frag reads done
        *(us8*)wA0 = cvt_us8(rA0a, rA0b);
        *(us8*)wA1 = cvt_us8(rA1a, rA1b);
        *(us8*)wB0 = rB0; *(us8*)wB1 = rB1;
        __syncthreads();
        if (step < 31) {                    // prefetch next K-slice
            pA0 += BK; pA1 += BK; pB0 += BK; pB1 += BK;
            rA0a = *(const float4*)pA0; rA0b = *(const float4*)(pA0 + 4);
            rA1a = *(const float4*)pA1; rA1b = *(const float4*)(pA1 + 4);
            rB0 = *(const us8*)pB0; rB1 = *(const us8*)pB1;
        }
        f16x8 aF[4], bF[4];
        #pragma unroll
        for (int mi = 0; mi < 4; mi++)
            aF[mi] = *(const f16x8*)&sA[(wm + mi * 16 + l16) * LDT + quad * 8];
        #pragma unroll
        for (int ni = 0; ni < 4; ni++)
            bF[ni] = *(const f16x8*)&sB[(wn + ni * 16 + l16) * LDT + quad * 8];
        #pragma unroll
        for (int mi = 0; mi < 4; mi++)
            #pragma unroll
            for (int ni = 0; ni < 4; ni++)
                acc[mi][ni] = MFMA(aF[mi], bF[ni], acc[mi][ni]);
    }

    int h = (nbase >> 6) + (wave & 1);      // wave's 64-col span = one head
    if (which < 2) {
        unsigned short* OUT = ((which == 0) ? qh : kh) + (size_t)h * ROWS * DK;
        #pragma unroll
        for (int mi = 0; mi < 4; mi++)
            #pragma unroll
            for (int ni = 0; ni < 4; ni++)
                #pragma unroll
                for (int r = 0; r < 4; r++) {
                    int row = mbase + wm + mi * 16 + quad * 4 + r;
                    OUT[(size_t)row * DK + ni * 16 + l16] = f2h(acc[mi][ni][r]);
                }
    } else {
        unsigned short* OUT = vt + (size_t)h * DK * ROWS;
        #pragma unroll
        for (int mi = 0; mi < 4; mi++)
            #pragma unroll
            for (int ni = 0; ni < 4; ni++) {
                int dk   = ni * 16 + l16;
                int rowb = mbase + wm + mi * 16 + quad * 4;
                us4v pk;
                pk[0] = f2h(acc[mi][ni][0]); pk[1] = f2h(acc[mi][ni][1]);
                pk[2] = f2h(acc[mi][ni][2]); pk[3] = f2h(acc[mi][ni][3]);
                *(us4v*)(OUT + (size_t)dk * ROWS + rowb) = pk;
            }
    }
}

// ---------------------------------------------------------------------------
// K2: flash attention (round-7 form, frozen). XCD-swizzled, LDS-staged K/V,
// S^T softmax, per-wave P round-trip.
// ---------------------------------------------------------------------------
__global__ __launch_bounds__(256) void k2_attn(
    const unsigned short* __restrict__ qh,   // fp16 [H][ROWS][DK]
    const unsigned short* __restrict__ kh,   // fp16 [H][ROWS][DK]
    const unsigned short* __restrict__ vt,   // fp16 [H][DK][ROWS]
    unsigned short* __restrict__ x2)         // fp16 [ROWS][DM]
{
    __shared__ __align__(16) unsigned short ktile[64][72];
    __shared__ __align__(16) unsigned short vtile[64][72];
    __shared__ __align__(16) unsigned short pld[4][16][72];

    int bx = blockIdx.x;
    int xcd = bx & 7;
    int loc = bx >> 3;
    int hb  = xcd * 4 + (loc >> 5);
    int qt  = loc & 31;
    int h = hb >> 1, b = hb & 1;
    int qbase = qt * 64;

    const unsigned short* qhp = qh + ((size_t)h * ROWS + b * L_) * DK;
    const unsigned short* khp = kh + ((size_t)h * ROWS + b * L_) * DK;
    const unsigned short* vtp = vt + (size_t)h * DK * ROWS + b * L_;

    int wave = threadIdx.x >> 6, lane = threadIdx.x & 63;
    int quad = lane >> 4, l16 = lane & 15;
    int t = threadIdx.x;

    int qrow = qbase + wave * 16 + l16;
    f16x8 qb0 = ld8h(qhp + (size_t)qrow * DK + quad * 8);
    f16x8 qb1 = ld8h(qhp + (size_t)qrow * DK + 32 + quad * 8);

    float m_i = -1e30f, l_i = 0.0f;
    f32x4 o[4];
    #pragma unroll
    for (int nt = 0; nt < 4; nt++) o[nt] = (f32x4)0.0f;

    for (int kt = 0; kt < 32; kt++) {
        int kb = kt * 64;
        {
            const unsigned short* kg = khp + (size_t)kb * DK;
            #pragma unroll
            for (int i = 0; i < 2; i++) {
                int c = i * 256 + t;
                int key = c >> 3, ch = (c & 7) * 8;
                *(us8*)&ktile[key][ch] = *(const us8*)(kg + c * 8);
            }
            #pragma unroll
            for (int i = 0; i < 2; i++) {
                int c = i * 256 + t;
                int dk = c >> 3, ch = (c & 7) * 8;
                *(us8*)&vtile[dk][ch] = *(const us8*)(vtp + (size_t)dk * ROWS + kb + ch);
            }
        }
        __syncthreads();

        f32x4 s[4];
        #pragma unroll
        for (int nt = 0; nt < 4; nt++) s[nt] = (f32x4)0.0f;
        #pragma unroll
        for (int nt = 0; nt < 4; nt++) {
            f16x8 ka0 = *(const f16x8*)&ktile[nt * 16 + l16][quad * 8];
            f16x8 ka1 = *(const f16x8*)&ktile[nt * 16 + l16][32 + quad * 8];
            s[nt] = MFMA(ka0, qb0, s[nt]);
            s[nt] = MFMA(ka1, qb1, s[nt]);
        }

        float mx = s[0][0];
        #pragma unroll
        for (int nt = 0; nt < 4; nt++)
            #pragma unroll
            for (int r = 0; r < 4; r++) mx = fmaxf(mx, s[nt][r]);
        mx = fmaxf(mx, __shfl_xor(mx, 16));
        mx = fmaxf(mx, __shfl_xor(mx, 32));
        float mnew  = fmaxf(m_i, mx);
        float alpha = __expf(m_i - mnew);
        float rs = 0.0f;
        #pragma unroll
        for (int nt = 0; nt < 4; nt++)
            #pragma unroll
            for (int r = 0; r < 4; r++) {
                float pv = __expf(s[nt][r] - mnew);
                s[nt][r] = pv;
                rs += pv;
            }
        rs += __shfl_xor(rs, 16);
        rs += __shfl_xor(rs, 32);
        l_i = l_i * alpha + rs;
        m_i = mnew;

        #pragma unroll
        for (int r = 0; r < 4; r++) {
            float av = __shfl(alpha, quad * 4 + r);
            #pragma unroll
            for (int nt = 0; nt < 4; nt++) o[nt][r] *= av;
        }

        #pragma unroll
        for (int nt = 0; nt < 4; nt++) {
            us4v pk;
            pk[0] = f2h(s[nt][0]); pk[1] = f2h(s[nt][1]);
            pk[2] = f2h(s[nt][2]); pk[3] = f2h(s[nt][3]);
            *(us4v*)&pld[wave][l16][nt * 16 + quad * 4] = pk;
        }

        #pragma unroll
        for (int kk = 0; kk < 2; kk++) {
            f16x8 pa = *(const f16x8*)&pld[wave][l16][kk * 32 + quad * 8];
            #pragma unroll
            for (int nt = 0; nt < 4; nt++) {
                f16x8 vb = *(const f16x8*)&vtile[nt * 16 + l16][kk * 32 + quad * 8];
                o[nt] = MFMA(pa, vb, o[nt]);
            }
        }
        __syncthreads();
    }

    float linv = 1.0f / l_i;
    #pragma unroll
    for (int r = 0; r < 4; r++) {
        float lv = __shfl(linv, quad * 4 + r);
        int row = qbase + wave * 16 + quad * 4 + r;
        #pragma unroll
        for (int nt = 0; nt < 4; nt++) {
            int col = nt * 16 + l16;
            float qv = h2f(qhp[(size_t)row * DK + col]);
            float val = o[nt][r] * lv * qv;
            x2[((size_t)b * L_ + row) * DM + h * DK + col] = f2h(val);
        }
    }
}

// ---------------------------------------------------------------------------
// K3: output projection as staged GEMM (same structure as K1):
// out[4096x1024] = X2 @ w_proj^T + bias, 128x128 tile, BK=32, f32 out.
// ---------------------------------------------------------------------------
__global__ __launch_bounds__(256) void k3_out_proj(
    const unsigned short* __restrict__ x2,     // fp16 [ROWS][DM]
    const unsigned short* __restrict__ wph,    // fp16 [DM][DM] (row = out dim)
    const float* __restrict__ bias,
    float* __restrict__ out)
{
    __shared__ __align__(16) unsigned short sA[128 * LDT];
    __shared__ __align__(16) unsigned short sB[128 * LDT];

    int bx = blockIdx.x;
    int mbase = (bx >> 3) * 128;
    int nbase = (bx & 7) * 128;

    int t = threadIdx.x;
    int wave = t >> 6, lane = t & 63, quad = lane >> 4, l16 = lane & 15;
    int wm = (wave >> 1) * 64, wn = (wave & 1) * 64;

    int ar0 = t >> 2,         ac0 = t & 3;
    int ar1 = (256 + t) >> 2, ac1 = t & 3;
    const unsigned short* pA0 = x2 + (size_t)(mbase + ar0) * DM + ac0 * 8;
    const unsigned short* pA1 = x2 + (size_t)(mbase + ar1) * DM + ac1 * 8;
    const unsigned short* pB0 = wph + (size_t)(nbase + ar0) * DM + ac0 * 8;
    const unsigned short* pB1 = wph + (size_t)(nbase + ar1) * DM + ac1 * 8;
    unsigned short* wA0 = &sA[ar0 * LDT + ac0 * 8];
    unsigned short* wA1 = &sA[ar1 * LDT + ac1 * 8];
    unsigned short* wB0 = &sB[ar0 * LDT + ac0 * 8];
    unsigned short* wB1 = &sB[ar1 * LDT + ac1 * 8];

    f32x4 acc[4][4];
    #pragma unroll
    for (int mi = 0; mi < 4; mi++)
        #pragma unroll
        for (int ni = 0; ni < 4; ni++) acc[mi][ni] = (f32x4)0.0f;

    us8 rA0 = *(const us8*)pA0, rA1 = *(const us8*)pA1;
    us8 rB0 = *(const us8*)pB0, rB1 = *(const us8*)pB1;

    for (int step = 0; step < 32; step++) {
        if (step) __syncthreads();
        *(us8*)wA0 = rA0; *(us8*)wA1 = rA1;
        *(us8*)wB0 = rB0; *(us8*)wB1 = rB1;
        __syncthreads();
        if (step < 31) {
            pA0 += BK; pA1 += BK; pB0 += BK; pB1 += BK;
            rA0 = *(const us8*)pA0; rA1 = *(const us8*)pA1;
            rB0 = *(const us8*)pB0; rB1 = *(const us8*)pB1;
        }
        f16x8 aF[4], bF[4];
        #pragma unroll
        for (int mi = 0; mi < 4; mi++)
            aF[mi] = *(const f16x8*)&sA[(wm + mi * 16 + l16) * LDT + quad * 8];
        #pragma unroll
        for (int ni = 0; ni < 4; ni++)
            bF[ni] = *(const f16x8*)&sB[(wn + ni * 16 + l16) * LDT + quad * 8];
        #pragma unroll
        for (int mi = 0; mi < 4; mi++)
            #pragma unroll
            for (int ni = 0; ni < 4; ni++)
                acc[mi][ni] = MFMA(aF[mi], bF[ni], acc[mi][ni]);
    }

    float bv[4];
    #pragma unroll
    for (int ni = 0; ni < 4; ni++) bv[ni] = bias[nbase + wn + ni * 16 + l16];

    #pragma unroll
    for (int mi = 0; mi < 4; mi++)
        #pragma unroll
        for (int ni = 0; ni < 4; ni++)
            #pragma unroll
            for (int r = 0; r < 4; r++) {
                int row = mbase + wm + mi * 16 + quad * 4 + r;
                int col = nbase + wn + ni * 16 + l16;
                out[(size_t)row * DM + col] = acc[mi][ni][r] + bv[ni];
            }
}

// ---------------------------------------------------------------------------
extern "C" void kernel_launch(void* const* d_in, const int* in_sizes, int n_in,
                              void* d_out, int out_size, void* d_ws, size_t ws_size,
                              hipStream_t stream)
{
    const float* q     = (const float*)d_in[0];
    const float* k     = (const float*)d_in[1];
    const float* v     = (const float*)d_in[2];
    const float* wqs   = (const float*)d_in[3];
    const float* wks   = (const float*)d_in[4];
    const float* wvs   = (const float*)d_in[5];
    const float* wproj = (const float*)d_in[6];
    const float* bproj = (const float*)d_in[7];
    float* out = (float*)d_out;

    char* ws = (char*)d_ws;
    #define MB (size_t)(1024 * 1024)
    unsigned short* wt  = (unsigned short*)(ws);            // 6 MB
    unsigned short* wph = (unsigned short*)(ws + 6  * MB);  // 2 MB
    unsigned short* qh  = (unsigned short*)(ws + 8  * MB);  // 8 MB
    unsigned short* kh  = (unsigned short*)(ws + 16 * MB);  // 8 MB
    unsigned short* vt  = (unsigned short*)(ws + 24 * MB);  // 8 MB
    unsigned short* x2  = (unsigned short*)(ws + 32 * MB);  // 8 MB (total 40 MB)

    kcvt<<<dim3((DM * DM) / (256 * 8)), dim3(256), 0, stream>>>(wproj, wph);
    k0_transpose_w<<<dim3(3 * H_ * 16), dim3(256), 0, stream>>>(wqs, wks, wvs, wt);

    k1_proj_qkv<<<dim3(3 * 32 * 8), dim3(256), 0, stream>>>(q, k, v, wt, qh, kh, vt);
    k2_attn<<<dim3(H_ * B_ * 32), dim3(256), 0, stream>>>(qh, kh, vt, x2);
    k3_out_proj<<<dim3(32 * 8), dim3(256), 0, stream>>>(x2, wph, bproj, out);
}